// Round 3
// baseline (382.651 us; speedup 1.0000x reference)
//
#include <hip/hip_runtime.h>
#include <stdint.h>

#define HW 262144            // 512*512
#define ACQ_N 2097152        // 8*1*512*512
#define SREG 69632           // slots per class region = 65536 + 4096 slack (18 sigma)
#define NREG3 208896         // 3*SREG slots per batch (classes 1..3)

// hw-native transcendentals (1 instr each)
#define LOG2F(x) __builtin_amdgcn_logf(x)
#define EXP2F(x) __builtin_amdgcn_exp2f(x)
#define SQRTF(x) __builtin_amdgcn_sqrtf(x)
#define RCPF(x)  __builtin_amdgcn_rcpf(x)

#define ROTL(x, r) __builtin_amdgcn_alignbit((x), (x), (32 - (r)) & 31)

// ---------- host-side threefry2x32 for key derivation ----------
static inline void tf2x32_host(uint32_t k0, uint32_t k1, uint32_t c0, uint32_t c1,
                               uint32_t& o0, uint32_t& o1) {
  const uint32_t ks2 = k0 ^ k1 ^ 0x1BD11BDAu;
  uint32_t x0 = c0 + k0, x1 = c1 + k1;
#define TFR(r) { x0 += x1; x1 = (x1 << (r)) | (x1 >> (32 - (r))); x1 ^= x0; }
  TFR(13) TFR(15) TFR(26) TFR(6)
  x0 += k1;  x1 += ks2 + 1u;
  TFR(17) TFR(29) TFR(16) TFR(24)
  x0 += ks2; x1 += k0 + 2u;
  TFR(13) TFR(15) TFR(26) TFR(6)
  x0 += k0;  x1 += k1 + 3u;
  TFR(17) TFR(29) TFR(16) TFR(24)
  x0 += k1;  x1 += ks2 + 4u;
  TFR(13) TFR(15) TFR(26) TFR(6)
  x0 += ks2; x1 += k0 + 5u;
#undef TFR
  o0 = x0; o1 = x1;
}

// device: partitionable random_bits(32) for counter (0, idx): o0^o1
__device__ __forceinline__ uint32_t rbits32(uint32_t k0, uint32_t k1, uint32_t idx) {
  const uint32_t ks2 = k0 ^ k1 ^ 0x1BD11BDAu;
  uint32_t x0 = k0, x1 = idx + k1;
#define TFR(r) { x0 += x1; x1 = ROTL(x1, r); x1 ^= x0; }
  TFR(13) TFR(15) TFR(26) TFR(6)
  x0 += k1;  x1 += ks2 + 1u;
  TFR(17) TFR(29) TFR(16) TFR(24)
  x0 += ks2; x1 += k0 + 2u;
  TFR(13) TFR(15) TFR(26) TFR(6)
  x0 += k0;  x1 += k1 + 3u;
  TFR(17) TFR(29) TFR(16) TFR(24)
  x0 += k1;  x1 += ks2 + 4u;
  TFR(13) TFR(15) TFR(26) TFR(6)
  x0 += ks2; x1 += k0 + 5u;
#undef TFR
  return x0 ^ x1;
}

__device__ __forceinline__ float unit_from_bits(uint32_t b) {
  return __uint_as_float((b >> 9) | 0x3F800000u) - 1.0f;
}

// z = sqrt(2)*erfinv(x), Giles poly pre-scaled by sqrt(2); far branch real-branched.
__device__ __forceinline__ float sqrt2_erfinv(float x) {
  float ome = fmaf(-x, x, 1.0f);
  float w = -0.69314718056f * LOG2F(ome);
  float wn = w - 2.5f;
  float p = 3.974065e-08f;
  p = fmaf(p, wn, 4.854641e-07f);
  p = fmaf(p, wn, -4.982823e-06f);
  p = fmaf(p, wn, -6.210531e-06f);
  p = fmaf(p, wn, 3.091200e-04f);
  p = fmaf(p, wn, -1.773035e-03f);
  p = fmaf(p, wn, -5.908135e-03f);
  p = fmaf(p, wn, 3.488029e-01f);
  p = fmaf(p, wn, 2.123314e+00f);
  if (__builtin_expect(w >= 5.0f, 0)) {
    float wf = SQRTF(w) - 3.0f;
    float q = -2.831458e-04f;
    q = fmaf(q, wf, 1.427657e-04f);
    q = fmaf(q, wf, 1.908260e-03f);
    q = fmaf(q, wf, -5.195013e-03f);
    q = fmaf(q, wf, 8.116892e-03f);
    q = fmaf(q, wf, -1.0779791e-02f);
    q = fmaf(q, wf, 1.3348579e-02f);
    q = fmaf(q, wf, 1.416582e+00f);
    q = fmaf(q, wf, 4.006434e+00f);
    p = q;
  }
  return p * x;
}

// ---------- specialized frame loops (class-pure, branches hoisted) ----------
__device__ __forceinline__ float loop_fg(float base, float fw, float fa, float gw,
                                         uint32_t idx, int nf,
                                         uint32_t ku0, uint32_t ku1,
                                         uint32_t kn0, uint32_t kn1) {
  float nfa = -fa, fac = fa * 0.52876637294f;
  float acc = 0.0f;
#pragma unroll 2
  for (int f = 0; f < nf; ++f) {
    uint32_t ub = rbits32(ku0, ku1, idx);
    uint32_t nb = rbits32(kn0, kn1, idx);
    idx += (uint32_t)HW;
    float u = fminf(fmaxf(unit_from_bits(ub), 1e-6f), 0.999999f);
    float pw = EXP2F(fmaf(nfa, LOG2F(-LOG2F(u)), fac));
    float z = sqrt2_erfinv(fmaf(unit_from_bits(nb), 2.0f, -0.99999994f));
    float t = fmaf(gw, z, fmaf(fw, pw, base));
    acc += fminf(fmaxf(t, 0.0f), 1.0f);
  }
  return acc * RCPF((float)nf);
}

__device__ __forceinline__ float loop_f(float base, float fw, float fa,
                                        uint32_t idx, int nf,
                                        uint32_t ku0, uint32_t ku1) {
  float nfa = -fa, fac = fa * 0.52876637294f;
  float acc = 0.0f;
#pragma unroll 4
  for (int f = 0; f < nf; ++f) {
    uint32_t ub = rbits32(ku0, ku1, idx);
    idx += (uint32_t)HW;
    float u = fminf(fmaxf(unit_from_bits(ub), 1e-6f), 0.999999f);
    float pw = EXP2F(fmaf(nfa, LOG2F(-LOG2F(u)), fac));
    acc += fminf(fmaxf(fmaf(fw, pw, base), 0.0f), 1.0f);
  }
  return acc * RCPF((float)nf);
}

__device__ __forceinline__ float loop_g(float base, float gw,
                                        uint32_t idx, int nf,
                                        uint32_t kn0, uint32_t kn1) {
  float acc = 0.0f;
#pragma unroll 4
  for (int f = 0; f < nf; ++f) {
    uint32_t nb = rbits32(kn0, kn1, idx);
    idx += (uint32_t)HW;
    float z = sqrt2_erfinv(fmaf(unit_from_bits(nb), 2.0f, -0.99999994f));
    acc += fminf(fmaxf(fmaf(gw, z, base), 0.0f), 1.0f);
  }
  return acc * RCPF((float)nf);
}

// ================= compacted path (atomic region allocation) =============
// ws: float partial[512] @0 ; u32 counters[8][4] @2048 ;
//     u32 remarr[8][NREG3] @4096 ; float4 packed[8][NREG3] @4096+8*NREG3*4
// Class regions per batch: class c in {1,2,3} -> slots [(c-1)*SREG, (c-1)*SREG+count_c).
// Slot order within a region is atomic-arrival order (arbitrary) — rem travels
// with packed so any permutation is correct.

// phase 1: per-(batch,chunk) bias partials; block 0 zeros the class counters.
__global__ __launch_bounds__(256) void bias_partial(const float* __restrict__ inp,
                                                    float* __restrict__ partial,
                                                    uint32_t* __restrict__ counters) {
  if (blockIdx.x == 0 && threadIdx.x < 32) counters[threadIdx.x] = 0u;
  int blk = blockIdx.x;
  int b = blk >> 6, chunk = blk & 63;
  const float4* src = (const float4*)(inp + ((size_t)b * 5 + 1) * HW
                                          + (size_t)chunk * 4096);
  int t = threadIdx.x;
  float s = 0.0f;
#pragma unroll
  for (int k = 0; k < 4; ++k) {
    float4 v = src[t + k * 256];
    s += (v.x + v.y) + (v.z + v.w);
  }
  for (int off = 32; off; off >>= 1) s += __shfl_down(s, off);
  __shared__ float ws4[4];
  if ((t & 63) == 0) ws4[t >> 6] = s;
  __syncthreads();
  if (t == 0) partial[blk] = ws4[0] + ws4[1] + ws4[2] + ws4[3];
}

// phase 2 (R3): 2048 blocks (8 batches x 256 subchunks, 1024 px each) for 4x TLP.
// Prephase loads ALL operands into registers (16 loads in flight), classifies,
// allocates region bases with one atomicAdd per (wave,class). After the single
// barrier the main loop is pure compute + stores (zero global loads).
__global__ __launch_bounds__(256) void scatter_pack(const float* __restrict__ inp,
                                                    const float* __restrict__ partial,
                                                    uint32_t* __restrict__ counters,
                                                    uint32_t* __restrict__ remarr,
                                                    float4* __restrict__ packed,
                                                    float* __restrict__ out) {
  int blk = blockIdx.x;                 // 2048 blocks
  int b = blk >> 8, sub = blk & 255;
  int tid = threadIdx.x, lane = tid & 63;
  const float* pb = inp + (size_t)b * 5 * HW;
  uint64_t below = (1ull << lane) - 1ull;
  int base_i = sub << 10;

  __shared__ float s_bias;
  // bias finalize (wave 0)
  if (tid < 64) {
    float s = partial[(b << 6) | tid];
    for (int o = 32; o; o >>= 1) s += __shfl_down(s, o);
    if (tid == 0) s_bias = fmaxf(s * (1.0f / 262144.0f), 0.0f);
  }

  // prephase: load 4 channels x 4 slices into regs, classify, count per wave
  float img4[4], fw4[4], fa4[4], gw4[4];
  uint32_t cls4[4];
  uint32_t wc1 = 0, wc2 = 0, wc3 = 0;
#pragma unroll
  for (int k = 0; k < 4; ++k) {
    int i = base_i + (k << 8) + tid;
    img4[k]  = pb[i];
    float f2 = pb[2 * HW + i];
    float f3 = pb[3 * HW + i];
    float f4 = pb[4 * HW + i];
    fw4[k] = fmaxf(f2, 0.0f);
    fa4[k] = fmaxf(f3, 0.0f);
    gw4[k] = fmaxf(f4, 0.0f);
    uint32_t cls = (f2 > 0.0f ? 1u : 0u) | (f4 > 0.0f ? 2u : 0u);
    cls4[k] = cls;
    wc1 += (uint32_t)__popcll(__ballot(cls == 1u));
    wc2 += (uint32_t)__popcll(__ballot(cls == 2u));
    wc3 += (uint32_t)__popcll(__ballot(cls == 3u));
  }
  // one atomicAdd per (wave, class): wave-uniform region bases
  uint32_t b1 = 0, b2 = 0, b3 = 0;
  if (lane == 0) {
    b1 = atomicAdd(&counters[(b << 2) | 1], wc1);
    b2 = atomicAdd(&counters[(b << 2) | 2], wc2);
    b3 = atomicAdd(&counters[(b << 2) | 3], wc3);
  }
  uint32_t run1 = __shfl(b1, 0), run2 = __shfl(b2, 0), run3 = __shfl(b3, 0);

  __syncthreads();                       // for s_bias only
  float bias = s_bias;

  uint32_t* rbase = remarr + (size_t)b * NREG3;
  float4*   kbase = packed + (size_t)b * NREG3;
  float*    outa  = out + (size_t)b * HW;
  float*    outc  = out + ACQ_N + (size_t)b * HW;

#pragma unroll
  for (int k = 0; k < 4; ++k) {
    int i = base_i + (k << 8) + tid;
    float fw = fw4[k], fa = fa4[k], gw = gw4[k];
    float basev = img4[k] + bias;
    // center = clip(base + fw*(1/(fa+1))^fa, 0, 1)  (coalesced write)
    float cpw = EXP2F(-fa * LOG2F(fa + 1.0f));
    float ctr = fminf(fmaxf(fmaf(fw, cpw, basev), 0.0f), 1.0f);
    outc[i] = ctr;

    uint32_t cls = cls4[k];
    if (cls == 0u) outa[i] = ctr;        // fw==0 && gw==0: acquired == center

    uint64_t ba1 = __ballot(cls == 1u);
    uint64_t ba2 = __ballot(cls == 2u);
    uint64_t ba3 = __ballot(cls == 3u);
    if (cls != 0u) {
      uint64_t own  = (cls == 1u) ? ba1 : ((cls == 2u) ? ba2 : ba3);
      uint32_t rbas = (cls == 1u) ? run1 : ((cls == 2u) ? run2 : run3);
      uint32_t roff = (cls - 1u) * (uint32_t)SREG + rbas + (uint32_t)__popcll(own & below);
      rbase[roff] = (uint32_t)i;
      kbase[roff] = make_float4(basev, fw, fa, gw);
    }
    run1 += (uint32_t)__popcll(ba1);
    run2 += (uint32_t)__popcll(ba2);
    run3 += (uint32_t)__popcll(ba3);
  }
}

// phase 3: coalesced packed reads, class-pure by REGION (no classification).
// Grid (272, 3, 8): x = slot-block, y = 0..2 -> class 3,2,1 (heavy first),
// z = batch. Dispatch is x-fastest -> batch-major, class-3 first (the proven
// L2-friendly order; batch-interleave regressed in R1).
__global__ __launch_bounds__(256) void acquire_packed(
    const int* __restrict__ frames, const uint32_t* __restrict__ counters,
    const uint32_t* __restrict__ remarr, const float4* __restrict__ packed,
    float* __restrict__ out,
    uint32_t ku0, uint32_t ku1, uint32_t kn0, uint32_t kn1) {
  int c = 3 - (int)blockIdx.y;                 // class 3, 2, 1
  int b = (int)blockIdx.z;
  uint32_t cnt = counters[(b << 2) | c];
  uint32_t slot = ((uint32_t)blockIdx.x << 8) | (uint32_t)threadIdx.x;
  if (((uint32_t)blockIdx.x << 8) >= cnt) return;   // whole block past region end
  if (slot < cnt) {
    size_t roff = (size_t)b * NREG3 + (size_t)(c - 1) * SREG + slot;
    float4 op = packed[roff];                  // coalesced 16 B
    uint32_t rem = remarr[roff];
    float base = op.x, fw = op.y, fa = op.z, gw = op.w;
    int nf = frames[b];                        // block-uniform
    uint32_t idx = ((uint32_t)b << 22) + rem;
    float res;
    if (c == 3)      res = loop_fg(base, fw, fa, gw, idx, nf, ku0, ku1, kn0, kn1);
    else if (c == 1) res = loop_f(base, fw, fa, idx, nf, ku0, ku1);
    else             res = loop_g(base, gw, idx, nf, kn0, kn1);
    out[(size_t)b * HW + rem] = res;
  }
}

// ================= plain tier (proven fallback, batch-major) =================
__global__ __launch_bounds__(256) void bias_partial_plain(const float* __restrict__ inp,
                                                          float* __restrict__ partial) {
  int blk = blockIdx.x;
  int b = blk >> 6, chunk = blk & 63;
  const float4* src = (const float4*)(inp + ((size_t)b * 5 + 1) * HW
                                          + (size_t)chunk * 4096);
  int t = threadIdx.x;
  float s = 0.0f;
#pragma unroll
  for (int k = 0; k < 4; ++k) {
    float4 v = src[t + k * 256];
    s += (v.x + v.y) + (v.z + v.w);
  }
  for (int off = 32; off; off >>= 1) s += __shfl_down(s, off);
  __shared__ float ws4[4];
  if ((t & 63) == 0) ws4[t >> 6] = s;
  __syncthreads();
  if (t == 0) partial[blk] = ws4[0] + ws4[1] + ws4[2] + ws4[3];
}

__global__ __launch_bounds__(256) void acquire_plain(
    const float* __restrict__ inp, const int* __restrict__ frames,
    const float* __restrict__ partial, float* __restrict__ out,
    uint32_t ku0, uint32_t ku1, uint32_t kn0, uint32_t kn1) {
  int b = blockIdx.x >> 10;
  int rem = ((blockIdx.x & 1023) << 8) | threadIdx.x;
  __shared__ float s_bias;
  if (threadIdx.x < 64) {
    float s = partial[(b << 6) | threadIdx.x];
    for (int off = 32; off; off >>= 1) s += __shfl_down(s, off);
    if (threadIdx.x == 0) s_bias = fmaxf(s * (1.0f / 262144.0f), 0.0f);
  }
  const float* pb = inp + (size_t)b * 5 * HW;
  float img = pb[rem];
  float fw  = fmaxf(pb[2 * HW + rem], 0.0f);
  float fa  = fmaxf(pb[3 * HW + rem], 0.0f);
  float gw  = fmaxf(pb[4 * HW + rem], 0.0f);
  __syncthreads();
  float base = img + s_bias;
  int nf = frames[b];
  uint32_t idx = ((uint32_t)b << 22) + (uint32_t)rem;
  float res = loop_fg(base, fw, fa, gw, idx, nf, ku0, ku1, kn0, kn1);
  out[(size_t)b * HW + rem] = res;
  float cpw = EXP2F(-fa * LOG2F(fa + 1.0f));
  out[ACQ_N + (size_t)b * HW + rem] = fminf(fmaxf(fmaf(fw, cpw, base), 0.0f), 1.0f);
}

extern "C" void kernel_launch(void* const* d_in, const int* in_sizes, int n_in,
                              void* d_out, int out_size, void* d_ws, size_t ws_size,
                              hipStream_t stream) {
  const float* inp    = (const float*)d_in[0];
  const int*   frames = (const int*)d_in[1];
  float* out = (float*)d_out;

  // jax_threefry_partitionable=True: split(key(42)) foldlike:
  // ku = cipher((0,42),(0,0)), kn = cipher((0,42),(0,1))
  uint32_t ku0, ku1, kn0, kn1;
  tf2x32_host(0u, 42u, 0u, 0u, ku0, ku1);
  tf2x32_host(0u, 42u, 0u, 1u, kn0, kn1);

  float*    partial  = (float*)d_ws;                     // 512 f32
  uint32_t* counters = (uint32_t*)((char*)d_ws + 2048);  // 8*4 u32
  const size_t need_full = 4096 + (size_t)8 * NREG3 * 4 + (size_t)8 * NREG3 * 16;

  if (ws_size >= need_full) {
    uint32_t* remarr = (uint32_t*)((char*)d_ws + 4096);
    float4*   packed = (float4*)((char*)d_ws + 4096 + (size_t)8 * NREG3 * 4);
    bias_partial<<<dim3(512), dim3(256), 0, stream>>>(inp, partial, counters);
    scatter_pack<<<dim3(2048), dim3(256), 0, stream>>>(inp, partial, counters,
                                                       remarr, packed, out);
    acquire_packed<<<dim3(272, 3, 8), dim3(256), 0, stream>>>(frames, counters,
                                                              remarr, packed, out,
                                                              ku0, ku1, kn0, kn1);
  } else {
    bias_partial_plain<<<dim3(512), dim3(256), 0, stream>>>(inp, partial);
    acquire_plain<<<dim3(8192), dim3(256), 0, stream>>>(inp, frames, partial, out,
                                                        ku0, ku1, kn0, kn1);
  }
}

// Round 4
// 156.448 us; speedup vs baseline: 2.4459x; 2.4459x over previous
//
#include <hip/hip_runtime.h>
#include <stdint.h>

#define HW 262144            // 512*512
#define ACQ_N 2097152        // 8*1*512*512
#define SREG 69632           // slots per class region = 65536 + 4096 slack (18 sigma)
#define NREG3 208896         // 3*SREG slots per batch (classes 1..3)

// each (batch,class) counter on its OWN 128-byte line (R3 post-mortem: all
// atomics on one line serialized the whole scatter kernel)
#define CNT(b, c) ((((b) << 2) | (c)) << 5)

// hw-native transcendentals (1 instr each)
#define LOG2F(x) __builtin_amdgcn_logf(x)
#define EXP2F(x) __builtin_amdgcn_exp2f(x)
#define SQRTF(x) __builtin_amdgcn_sqrtf(x)
#define RCPF(x)  __builtin_amdgcn_rcpf(x)

#define ROTL(x, r) __builtin_amdgcn_alignbit((x), (x), (32 - (r)) & 31)

// ---------- host-side threefry2x32 for key derivation ----------
static inline void tf2x32_host(uint32_t k0, uint32_t k1, uint32_t c0, uint32_t c1,
                               uint32_t& o0, uint32_t& o1) {
  const uint32_t ks2 = k0 ^ k1 ^ 0x1BD11BDAu;
  uint32_t x0 = c0 + k0, x1 = c1 + k1;
#define TFR(r) { x0 += x1; x1 = (x1 << (r)) | (x1 >> (32 - (r))); x1 ^= x0; }
  TFR(13) TFR(15) TFR(26) TFR(6)
  x0 += k1;  x1 += ks2 + 1u;
  TFR(17) TFR(29) TFR(16) TFR(24)
  x0 += ks2; x1 += k0 + 2u;
  TFR(13) TFR(15) TFR(26) TFR(6)
  x0 += k0;  x1 += k1 + 3u;
  TFR(17) TFR(29) TFR(16) TFR(24)
  x0 += k1;  x1 += ks2 + 4u;
  TFR(13) TFR(15) TFR(26) TFR(6)
  x0 += ks2; x1 += k0 + 5u;
#undef TFR
  o0 = x0; o1 = x1;
}

// device: partitionable random_bits(32) for counter (0, idx): o0^o1
__device__ __forceinline__ uint32_t rbits32(uint32_t k0, uint32_t k1, uint32_t idx) {
  const uint32_t ks2 = k0 ^ k1 ^ 0x1BD11BDAu;
  uint32_t x0 = k0, x1 = idx + k1;
#define TFR(r) { x0 += x1; x1 = ROTL(x1, r); x1 ^= x0; }
  TFR(13) TFR(15) TFR(26) TFR(6)
  x0 += k1;  x1 += ks2 + 1u;
  TFR(17) TFR(29) TFR(16) TFR(24)
  x0 += ks2; x1 += k0 + 2u;
  TFR(13) TFR(15) TFR(26) TFR(6)
  x0 += k0;  x1 += k1 + 3u;
  TFR(17) TFR(29) TFR(16) TFR(24)
  x0 += k1;  x1 += ks2 + 4u;
  TFR(13) TFR(15) TFR(26) TFR(6)
  x0 += ks2; x1 += k0 + 5u;
#undef TFR
  return x0 ^ x1;
}

__device__ __forceinline__ float unit_from_bits(uint32_t b) {
  return __uint_as_float((b >> 9) | 0x3F800000u) - 1.0f;
}

// z = sqrt(2)*erfinv(x), Giles poly pre-scaled by sqrt(2); far branch real-branched.
__device__ __forceinline__ float sqrt2_erfinv(float x) {
  float ome = fmaf(-x, x, 1.0f);
  float w = -0.69314718056f * LOG2F(ome);
  float wn = w - 2.5f;
  float p = 3.974065e-08f;
  p = fmaf(p, wn, 4.854641e-07f);
  p = fmaf(p, wn, -4.982823e-06f);
  p = fmaf(p, wn, -6.210531e-06f);
  p = fmaf(p, wn, 3.091200e-04f);
  p = fmaf(p, wn, -1.773035e-03f);
  p = fmaf(p, wn, -5.908135e-03f);
  p = fmaf(p, wn, 3.488029e-01f);
  p = fmaf(p, wn, 2.123314e+00f);
  if (__builtin_expect(w >= 5.0f, 0)) {
    float wf = SQRTF(w) - 3.0f;
    float q = -2.831458e-04f;
    q = fmaf(q, wf, 1.427657e-04f);
    q = fmaf(q, wf, 1.908260e-03f);
    q = fmaf(q, wf, -5.195013e-03f);
    q = fmaf(q, wf, 8.116892e-03f);
    q = fmaf(q, wf, -1.0779791e-02f);
    q = fmaf(q, wf, 1.3348579e-02f);
    q = fmaf(q, wf, 1.416582e+00f);
    q = fmaf(q, wf, 4.006434e+00f);
    p = q;
  }
  return p * x;
}

// ---------- specialized frame loops (class-pure, branches hoisted) ----------
__device__ __forceinline__ float loop_fg(float base, float fw, float fa, float gw,
                                         uint32_t idx, int nf,
                                         uint32_t ku0, uint32_t ku1,
                                         uint32_t kn0, uint32_t kn1) {
  float nfa = -fa, fac = fa * 0.52876637294f;
  float acc = 0.0f;
#pragma unroll 2
  for (int f = 0; f < nf; ++f) {
    uint32_t ub = rbits32(ku0, ku1, idx);
    uint32_t nb = rbits32(kn0, kn1, idx);
    idx += (uint32_t)HW;
    float u = fminf(fmaxf(unit_from_bits(ub), 1e-6f), 0.999999f);
    float pw = EXP2F(fmaf(nfa, LOG2F(-LOG2F(u)), fac));
    float z = sqrt2_erfinv(fmaf(unit_from_bits(nb), 2.0f, -0.99999994f));
    float t = fmaf(gw, z, fmaf(fw, pw, base));
    acc += fminf(fmaxf(t, 0.0f), 1.0f);
  }
  return acc * RCPF((float)nf);
}

__device__ __forceinline__ float loop_f(float base, float fw, float fa,
                                        uint32_t idx, int nf,
                                        uint32_t ku0, uint32_t ku1) {
  float nfa = -fa, fac = fa * 0.52876637294f;
  float acc = 0.0f;
#pragma unroll 4
  for (int f = 0; f < nf; ++f) {
    uint32_t ub = rbits32(ku0, ku1, idx);
    idx += (uint32_t)HW;
    float u = fminf(fmaxf(unit_from_bits(ub), 1e-6f), 0.999999f);
    float pw = EXP2F(fmaf(nfa, LOG2F(-LOG2F(u)), fac));
    acc += fminf(fmaxf(fmaf(fw, pw, base), 0.0f), 1.0f);
  }
  return acc * RCPF((float)nf);
}

__device__ __forceinline__ float loop_g(float base, float gw,
                                        uint32_t idx, int nf,
                                        uint32_t kn0, uint32_t kn1) {
  float acc = 0.0f;
#pragma unroll 4
  for (int f = 0; f < nf; ++f) {
    uint32_t nb = rbits32(kn0, kn1, idx);
    idx += (uint32_t)HW;
    float z = sqrt2_erfinv(fmaf(unit_from_bits(nb), 2.0f, -0.99999994f));
    acc += fminf(fmaxf(fmaf(gw, z, base), 0.0f), 1.0f);
  }
  return acc * RCPF((float)nf);
}

// ================= compacted path (atomic region allocation) =============
// ws: float partial[512] @0 ; u32 counters[1024] @4096 (each live counter on its
//     own 128B line via CNT()) ; u32 remarr[8][NREG3] @8192 ;
//     float4 packed[8][NREG3] @8192+8*NREG3*4
// Class regions per batch: class c in {1,2,3} -> slots [(c-1)*SREG, (c-1)*SREG+count_c).
// Slot order within a region is atomic-arrival order (arbitrary) — rem travels
// with packed so any permutation is correct.

// phase 1: per-(batch,chunk) bias partials; block 0 zeros the class counters.
__global__ __launch_bounds__(256) void bias_partial(const float* __restrict__ inp,
                                                    float* __restrict__ partial,
                                                    uint32_t* __restrict__ counters) {
  if (blockIdx.x == 0) {
    counters[threadIdx.x] = 0u;
    counters[256 + threadIdx.x] = 0u;
    counters[512 + threadIdx.x] = 0u;
    counters[768 + threadIdx.x] = 0u;
  }
  int blk = blockIdx.x;
  int b = blk >> 6, chunk = blk & 63;
  const float4* src = (const float4*)(inp + ((size_t)b * 5 + 1) * HW
                                          + (size_t)chunk * 4096);
  int t = threadIdx.x;
  float s = 0.0f;
#pragma unroll
  for (int k = 0; k < 4; ++k) {
    float4 v = src[t + k * 256];
    s += (v.x + v.y) + (v.z + v.w);
  }
  for (int off = 32; off; off >>= 1) s += __shfl_down(s, off);
  __shared__ float ws4[4];
  if ((t & 63) == 0) ws4[t >> 6] = s;
  __syncthreads();
  if (t == 0) partial[blk] = ws4[0] + ws4[1] + ws4[2] + ws4[3];
}

// phase 2 (R4): 2048 blocks, register-cached prephase (R3) + BLOCK-AGGREGATED
// atomics on PADDED counters (R3 post-mortem: per-wave atomics on one shared
// cache line serialized ~24K ops -> 205us). Now 3 atomics per block over 24
// independent lines.
__global__ __launch_bounds__(256) void scatter_pack(const float* __restrict__ inp,
                                                    const float* __restrict__ partial,
                                                    uint32_t* __restrict__ counters,
                                                    uint32_t* __restrict__ remarr,
                                                    float4* __restrict__ packed,
                                                    float* __restrict__ out) {
  int blk = blockIdx.x;                 // 2048 blocks: 8 batches x 256 subchunks
  int b = blk >> 8, sub = blk & 255;
  int tid = threadIdx.x, lane = tid & 63, wid = tid >> 6;
  const float* pb = inp + (size_t)b * 5 * HW;
  uint64_t below = (1ull << lane) - 1ull;
  int base_i = sub << 10;

  __shared__ float s_bias;
  __shared__ uint32_t swcnt[4][4];       // [wave][class]
  __shared__ uint32_t sbase[4];          // block's region base per class

  // bias finalize (wave 0)
  if (tid < 64) {
    float s = partial[(b << 6) | tid];
    for (int o = 32; o; o >>= 1) s += __shfl_down(s, o);
    if (tid == 0) s_bias = fmaxf(s * (1.0f / 262144.0f), 0.0f);
  }

  // prephase: load 4 channels x 4 slices into regs, classify, count per wave
  float img4[4], fw4[4], fa4[4], gw4[4];
  uint32_t cls4[4];
  uint32_t wc1 = 0, wc2 = 0, wc3 = 0;
#pragma unroll
  for (int k = 0; k < 4; ++k) {
    int i = base_i + (k << 8) + tid;
    img4[k]  = pb[i];
    float f2 = pb[2 * HW + i];
    float f3 = pb[3 * HW + i];
    float f4 = pb[4 * HW + i];
    fw4[k] = fmaxf(f2, 0.0f);
    fa4[k] = fmaxf(f3, 0.0f);
    gw4[k] = fmaxf(f4, 0.0f);
    uint32_t cls = (f2 > 0.0f ? 1u : 0u) | (f4 > 0.0f ? 2u : 0u);
    cls4[k] = cls;
    wc1 += (uint32_t)__popcll(__ballot(cls == 1u));
    wc2 += (uint32_t)__popcll(__ballot(cls == 2u));
    wc3 += (uint32_t)__popcll(__ballot(cls == 3u));
  }
  if (lane == 0) {
    swcnt[wid][1] = wc1; swcnt[wid][2] = wc2; swcnt[wid][3] = wc3;
  }
  __syncthreads();
  // 3 atomics per BLOCK, each counter on its own 128B line
  if (tid < 3) {
    int c = tid + 1;
    uint32_t tot = swcnt[0][c] + swcnt[1][c] + swcnt[2][c] + swcnt[3][c];
    sbase[c] = atomicAdd(&counters[CNT(b, c)], tot);
  }
  __syncthreads();

  uint32_t run1 = sbase[1], run2 = sbase[2], run3 = sbase[3];
#pragma unroll
  for (int w = 0; w < 4; ++w) {
    if (w < wid) { run1 += swcnt[w][1]; run2 += swcnt[w][2]; run3 += swcnt[w][3]; }
  }
  float bias = s_bias;

  uint32_t* rbase = remarr + (size_t)b * NREG3;
  float4*   kbase = packed + (size_t)b * NREG3;
  float*    outa  = out + (size_t)b * HW;
  float*    outc  = out + ACQ_N + (size_t)b * HW;

#pragma unroll
  for (int k = 0; k < 4; ++k) {
    int i = base_i + (k << 8) + tid;
    float fw = fw4[k], fa = fa4[k], gw = gw4[k];
    float basev = img4[k] + bias;
    // center = clip(base + fw*(1/(fa+1))^fa, 0, 1)  (coalesced write)
    float cpw = EXP2F(-fa * LOG2F(fa + 1.0f));
    float ctr = fminf(fmaxf(fmaf(fw, cpw, basev), 0.0f), 1.0f);
    outc[i] = ctr;

    uint32_t cls = cls4[k];
    if (cls == 0u) outa[i] = ctr;        // fw==0 && gw==0: acquired == center

    uint64_t ba1 = __ballot(cls == 1u);
    uint64_t ba2 = __ballot(cls == 2u);
    uint64_t ba3 = __ballot(cls == 3u);
    if (cls != 0u) {
      uint64_t own  = (cls == 1u) ? ba1 : ((cls == 2u) ? ba2 : ba3);
      uint32_t rbas = (cls == 1u) ? run1 : ((cls == 2u) ? run2 : run3);
      uint32_t roff = (cls - 1u) * (uint32_t)SREG + rbas + (uint32_t)__popcll(own & below);
      rbase[roff] = (uint32_t)i;
      kbase[roff] = make_float4(basev, fw, fa, gw);
    }
    run1 += (uint32_t)__popcll(ba1);
    run2 += (uint32_t)__popcll(ba2);
    run3 += (uint32_t)__popcll(ba3);
  }
}

// phase 3: coalesced packed reads, class-pure by REGION (no classification).
// Grid (272, 3, 8): x = slot-block, y = 0..2 -> class 3,2,1 (heavy first),
// z = batch. Dispatch is x-fastest -> batch-major, class-3 first (the proven
// L2-friendly order; batch-interleave regressed in R1).
__global__ __launch_bounds__(256) void acquire_packed(
    const int* __restrict__ frames, const uint32_t* __restrict__ counters,
    const uint32_t* __restrict__ remarr, const float4* __restrict__ packed,
    float* __restrict__ out,
    uint32_t ku0, uint32_t ku1, uint32_t kn0, uint32_t kn1) {
  int c = 3 - (int)blockIdx.y;                 // class 3, 2, 1
  int b = (int)blockIdx.z;
  uint32_t cnt = counters[CNT(b, c)];
  uint32_t slot = ((uint32_t)blockIdx.x << 8) | (uint32_t)threadIdx.x;
  if (((uint32_t)blockIdx.x << 8) >= cnt) return;   // whole block past region end
  if (slot < cnt) {
    size_t roff = (size_t)b * NREG3 + (size_t)(c - 1) * SREG + slot;
    float4 op = packed[roff];                  // coalesced 16 B
    uint32_t rem = remarr[roff];
    float base = op.x, fw = op.y, fa = op.z, gw = op.w;
    int nf = frames[b];                        // block-uniform
    uint32_t idx = ((uint32_t)b << 22) + rem;
    float res;
    if (c == 3)      res = loop_fg(base, fw, fa, gw, idx, nf, ku0, ku1, kn0, kn1);
    else if (c == 1) res = loop_f(base, fw, fa, idx, nf, ku0, ku1);
    else             res = loop_g(base, gw, idx, nf, kn0, kn1);
    out[(size_t)b * HW + rem] = res;
  }
}

// ================= plain tier (proven fallback, batch-major) =================
__global__ __launch_bounds__(256) void bias_partial_plain(const float* __restrict__ inp,
                                                          float* __restrict__ partial) {
  int blk = blockIdx.x;
  int b = blk >> 6, chunk = blk & 63;
  const float4* src = (const float4*)(inp + ((size_t)b * 5 + 1) * HW
                                          + (size_t)chunk * 4096);
  int t = threadIdx.x;
  float s = 0.0f;
#pragma unroll
  for (int k = 0; k < 4; ++k) {
    float4 v = src[t + k * 256];
    s += (v.x + v.y) + (v.z + v.w);
  }
  for (int off = 32; off; off >>= 1) s += __shfl_down(s, off);
  __shared__ float ws4[4];
  if ((t & 63) == 0) ws4[t >> 6] = s;
  __syncthreads();
  if (t == 0) partial[blk] = ws4[0] + ws4[1] + ws4[2] + ws4[3];
}

__global__ __launch_bounds__(256) void acquire_plain(
    const float* __restrict__ inp, const int* __restrict__ frames,
    const float* __restrict__ partial, float* __restrict__ out,
    uint32_t ku0, uint32_t ku1, uint32_t kn0, uint32_t kn1) {
  int b = blockIdx.x >> 10;
  int rem = ((blockIdx.x & 1023) << 8) | threadIdx.x;
  __shared__ float s_bias;
  if (threadIdx.x < 64) {
    float s = partial[(b << 6) | threadIdx.x];
    for (int off = 32; off; off >>= 1) s += __shfl_down(s, off);
    if (threadIdx.x == 0) s_bias = fmaxf(s * (1.0f / 262144.0f), 0.0f);
  }
  const float* pb = inp + (size_t)b * 5 * HW;
  float img = pb[rem];
  float fw  = fmaxf(pb[2 * HW + rem], 0.0f);
  float fa  = fmaxf(pb[3 * HW + rem], 0.0f);
  float gw  = fmaxf(pb[4 * HW + rem], 0.0f);
  __syncthreads();
  float base = img + s_bias;
  int nf = frames[b];
  uint32_t idx = ((uint32_t)b << 22) + (uint32_t)rem;
  float res = loop_fg(base, fw, fa, gw, idx, nf, ku0, ku1, kn0, kn1);
  out[(size_t)b * HW + rem] = res;
  float cpw = EXP2F(-fa * LOG2F(fa + 1.0f));
  out[ACQ_N + (size_t)b * HW + rem] = fminf(fmaxf(fmaf(fw, cpw, base), 0.0f), 1.0f);
}

extern "C" void kernel_launch(void* const* d_in, const int* in_sizes, int n_in,
                              void* d_out, int out_size, void* d_ws, size_t ws_size,
                              hipStream_t stream) {
  const float* inp    = (const float*)d_in[0];
  const int*   frames = (const int*)d_in[1];
  float* out = (float*)d_out;

  // jax_threefry_partitionable=True: split(key(42)) foldlike:
  // ku = cipher((0,42),(0,0)), kn = cipher((0,42),(0,1))
  uint32_t ku0, ku1, kn0, kn1;
  tf2x32_host(0u, 42u, 0u, 0u, ku0, ku1);
  tf2x32_host(0u, 42u, 0u, 1u, kn0, kn1);

  float*    partial  = (float*)d_ws;                     // 512 f32
  uint32_t* counters = (uint32_t*)((char*)d_ws + 4096);  // 1024 u32 (padded lines)
  const size_t need_full = 8192 + (size_t)8 * NREG3 * 4 + (size_t)8 * NREG3 * 16;

  if (ws_size >= need_full) {
    uint32_t* remarr = (uint32_t*)((char*)d_ws + 8192);
    float4*   packed = (float4*)((char*)d_ws + 8192 + (size_t)8 * NREG3 * 4);
    bias_partial<<<dim3(512), dim3(256), 0, stream>>>(inp, partial, counters);
    scatter_pack<<<dim3(2048), dim3(256), 0, stream>>>(inp, partial, counters,
                                                       remarr, packed, out);
    acquire_packed<<<dim3(272, 3, 8), dim3(256), 0, stream>>>(frames, counters,
                                                              remarr, packed, out,
                                                              ku0, ku1, kn0, kn1);
  } else {
    bias_partial_plain<<<dim3(512), dim3(256), 0, stream>>>(inp, partial);
    acquire_plain<<<dim3(8192), dim3(256), 0, stream>>>(inp, frames, partial, out,
                                                        ku0, ku1, kn0, kn1);
  }
}